// Round 15
// baseline (341.357 us; speedup 1.0000x reference)
//
#include <hip/hip_runtime.h>

constexpr int R_ = 5, H_ = 8, D_ = 16, C_ = 128;
constexpr int RH = R_ * H_;       // 40 softmax slots
constexpr int CAP = 56;           // per-row edge bucket capacity (deg ~ Poisson(16))
constexpr int RPB = 64;           // rows per coarse bin
constexpr int BCAP = 1280;        // records per coarse bin (mean 1024, +8 sigma)
constexpr int SC_BLOCKS = 2048;   // scores grid

typedef short bf16x8 __attribute__((ext_vector_type(8)));
typedef float f32x4 __attribute__((ext_vector_type(4)));

__device__ __forceinline__ unsigned short f2bf(float f) {
    unsigned int u = __float_as_uint(f);
    u += 0x7FFFu + ((u >> 16) & 1u);   // round-to-nearest-even
    return (unsigned short)(u >> 16);
}
__device__ __forceinline__ float bf2f(unsigned short b) {
    return __uint_as_float((unsigned int)b << 16);
}
// dot of 8 bf16 pairs packed in uint4
__device__ __forceinline__ float dot8(uint4 a, uint4 b) {
    const unsigned int* pa = (const unsigned int*)&a;
    const unsigned int* pb = (const unsigned int*)&b;
    float s = 0.f;
    #pragma unroll
    for (int u = 0; u < 4; ++u) {
        s += bf2f((unsigned short)pa[u]) * bf2f((unsigned short)pb[u]);
        s += bf2f((unsigned short)(pa[u] >> 16)) * bf2f((unsigned short)(pb[u] >> 16));
    }
    return s;
}

// ---- weights to bf16 (64 blocks) + alpha init (block 0) ----
__global__ __launch_bounds__(256) void wprep_init_kernel(const float* __restrict__ Wq,
                                                         const float* __restrict__ Wk,
                                                         const float* __restrict__ Wv,
                                                         const float* __restrict__ Wo,
                                                         const float* __restrict__ sa,
                                                         unsigned short* __restrict__ w3,
                                                         unsigned short* __restrict__ wo,
                                                         float* __restrict__ alpha) {
    int i = blockIdx.x * 256 + threadIdx.x;
    if (i < 16384) {
        w3[i]           = f2bf(Wq[i]);
        w3[16384 + i]   = f2bf(Wk[i]);
        w3[32768 + i]   = f2bf(Wv[i]);
        wo[i]           = f2bf(Wo[i]);
    }
    if (blockIdx.x == 0 && threadIdx.x < D_) {
        int t = threadIdx.x;
        float vals[H_];
        float mx = -1e30f;
        #pragma unroll
        for (int h = 0; h < H_; ++h) { vals[h] = sa[h * D_ + t]; mx = fmaxf(mx, vals[h]); }
        float sum = 0.0f;
        #pragma unroll
        for (int h = 0; h < H_; ++h) { vals[h] = expf(vals[h] - mx); sum += vals[h]; }
        float inv = 1.0f / sum;
        #pragma unroll
        for (int h = 0; h < H_; ++h) alpha[h * D_ + t] = vals[h] * inv;
    }
}

// ============ MFMA GEMM pieces (operand-swap + LDS W) ============

__device__ __forceinline__ void stage_tile(unsigned short* As, const float* __restrict__ src,
                                           int row0, int N) {
    int tid = threadIdx.x;
    #pragma unroll
    for (int it = 0; it < 4; ++it) {
        int g = tid + it * 256;       // 1024 groups of 8 bf16 (16B)
        int row = g >> 4, kg = g & 15;
        int grow = row0 + row;
        float4 f0 = make_float4(0.f, 0.f, 0.f, 0.f), f1 = f0;
        if (grow < N) {
            const float* p = src + (size_t)grow * C_ + kg * 8;
            f0 = *(const float4*)p;
            f1 = *(const float4*)(p + 4);
        }
        uint4 pk;
        pk.x = f2bf(f0.x) | ((unsigned int)f2bf(f0.y) << 16);
        pk.y = f2bf(f0.z) | ((unsigned int)f2bf(f0.w) << 16);
        pk.z = f2bf(f1.x) | ((unsigned int)f2bf(f1.y) << 16);
        pk.w = f2bf(f1.z) | ((unsigned int)f2bf(f1.w) << 16);
        *(uint4*)((char*)As + (row * 256 + ((kg * 16) ^ ((row & 7) << 4)))) = pk;
    }
}

// stage a 64x128 bf16 tile (already scaled) -> swizzled LDS
__device__ __forceinline__ void stage_bf_tile(unsigned short* As,
                                              const unsigned short* __restrict__ src,
                                              int row0, int N) {
    int tid = threadIdx.x;
    #pragma unroll
    for (int it = 0; it < 4; ++it) {
        int g = tid + it * 256;
        int row = g >> 4, kg = g & 15;
        int grow = row0 + row;
        uint4 v = make_uint4(0u, 0u, 0u, 0u);
        if (grow < N) v = *(const uint4*)(src + (size_t)grow * C_ + kg * 8);
        *(uint4*)((char*)As + (row * 256 + ((kg * 16) ^ ((row & 7) << 4)))) = v;
    }
}

__device__ __forceinline__ void stage_w(unsigned short* Ws, const unsigned short* __restrict__ w) {
    int tid = threadIdx.x;
    const uint4* src = (const uint4*)w;   // 2048 x 16B
    #pragma unroll
    for (int it = 0; it < 8; ++it) {
        int g = tid + it * 256;
        int row = g >> 4, kg = g & 15;
        uint4 v = src[g];
        *(uint4*)((char*)Ws + (row * 256 + ((kg * 16) ^ ((row & 7) << 4)))) = v;
    }
}

template <bool BF_OUT>
__device__ __forceinline__ void wave_gemm(const unsigned short* As,
                                          const unsigned short* Ws,
                                          const float* __restrict__ bias,
                                          float* __restrict__ outf,
                                          unsigned short* __restrict__ outb,
                                          int row0, int N) {
    int tid = threadIdx.x;
    int l = tid & 63, wave = tid >> 6;
    int lr = l & 15, lk = (l >> 4) * 8;
    int rowA = wave * 16 + lr;                 // x-row (B-operand free index)
    const char* xbase = (const char*)As + rowA * 256;
    int swx = (rowA & 7) << 4;
    f32x4 acc[8];
    #pragma unroll
    for (int n = 0; n < 8; ++n) acc[n] = (f32x4){0.f, 0.f, 0.f, 0.f};
    #pragma unroll
    for (int kk = 0; kk < 4; ++kk) {
        bf16x8 xb = *(const bf16x8*)(xbase + (((kk * 32 + lk) * 2) ^ swx));
        #pragma unroll
        for (int n = 0; n < 8; ++n) {
            int ch = n * 16 + lr;              // W channel (A-operand free index)
            bf16x8 wf = *(const bf16x8*)((const char*)Ws + ch * 256 +
                                         (((kk * 32 + lk) * 2) ^ ((ch & 7) << 4)));
            acc[n] = __builtin_amdgcn_mfma_f32_16x16x32_bf16(wf, xb, acc[n], 0, 0, 0);
        }
    }
    int xrow = row0 + wave * 16 + lr;
    int chb = (l >> 4) * 4;
    if (xrow < N) {
        #pragma unroll
        for (int n = 0; n < 8; ++n) {
            int ch = n * 16 + chb;
            float4 b4 = *(const float4*)(bias + ch);
            float v0 = acc[n][0] + b4.x, v1 = acc[n][1] + b4.y;
            float v2 = acc[n][2] + b4.z, v3 = acc[n][3] + b4.w;
            if (BF_OUT) {
                uint2 p;
                p.x = f2bf(v0) | ((unsigned int)f2bf(v1) << 16);
                p.y = f2bf(v2) | ((unsigned int)f2bf(v3) << 16);
                *(uint2*)(outb + (size_t)xrow * C_ + ch) = p;
            } else {
                *(float4*)(outf + (size_t)xrow * C_ + ch) = make_float4(v0, v1, v2, v3);
            }
        }
    }
}

// ==== fused dispatch: coarse-bin append (pass 1) interleaved 4:3 with qkv (MFMA) ====
__global__ __launch_bounds__(256) void fill_qkv_kernel(const int* __restrict__ ei,
                                                       const int* __restrict__ et,
                                                       int* __restrict__ bcnt,
                                                       int* __restrict__ bins,
                                                       const float* __restrict__ x,
                                                       const unsigned short* __restrict__ w3,
                                                       const float* __restrict__ bq,
                                                       const float* __restrict__ bk,
                                                       const float* __restrict__ bv,
                                                       unsigned short* __restrict__ q_bf,
                                                       unsigned short* __restrict__ k_bf,
                                                       unsigned short* __restrict__ v_bf,
                                                       int N, int E, int nfb, int nq3) {
    __shared__ unsigned short As[64 * 128];
    __shared__ unsigned short Ws[128 * 128];
    int bid = blockIdx.x;
    int u = bid / 7, r = bid - u * 7;
    if (r < 4) {                       // ---- pass 1: append to coarse bins (linear cursors) ----
        int fb = u * 4 + r;
        if (fb < nfb) {
            int i = fb * 256 + threadIdx.x;
            if (i < E) {
                int row = ei[i];
                int b = row >> 6;      // RPB = 64
                int pos = atomicAdd(&bcnt[b], 1);
                if (pos < BCAP) {
                    int rec = ((row & 63) << 23) | (et[i] << 20) | ei[E + i];
                    __builtin_nontemporal_store(rec, &bins[(size_t)b * BCAP + pos]);
                }
            }
        }
        return;
    }
    int qb = u * 3 + (r - 4);          // ---- qkv GEMM ----
    if (qb >= nq3) return;
    int rt = qb / 3, wsel = qb - rt * 3;
    int row0 = rt * 64;
    stage_tile(As, x, row0, N);
    stage_w(Ws, w3 + wsel * 16384);
    __syncthreads();
    if (wsel == 0)      wave_gemm<true>(As, Ws, bq, nullptr, q_bf, row0, N);
    else if (wsel == 1) wave_gemm<true>(As, Ws, bk, nullptr, k_bf, row0, N);
    else                wave_gemm<true>(As, Ws, bv, nullptr, v_bf, row0, N);
}

// ==== pass 2: per-bin scatter into em slots (LDS counters, L2-local writes) ====
__global__ __launch_bounds__(256) void binscat_kernel(const int* __restrict__ bins,
                                                      const int* __restrict__ bcnt,
                                                      int* __restrict__ em,
                                                      int* __restrict__ cnt, int N) {
    __shared__ int lcnt[RPB];
    int b = blockIdx.x;
    int t = threadIdx.x;
    if (t < RPB) lcnt[t] = 0;
    __syncthreads();
    int n = min(bcnt[b], BCAP);
    const int* src = bins + (size_t)b * BCAP;
    for (int i = t; i < n; i += 256) {
        int rec = src[i];
        int rl = (unsigned int)rec >> 23;           // row_local (6 bits)
        int pos = atomicAdd(&lcnt[rl], 1);
        if (pos < CAP)
            em[((size_t)b * RPB + rl) * CAP + pos] = rec & 0x7FFFFF;  // col | type<<20
    }
    __syncthreads();
    int row = b * RPB + t;
    if (t < RPB && row < N) cnt[row] = min(lcnt[t], CAP);
}

// final GEMM: out = outacc_bf(alpha pre-applied) @ Wo^T + bo
__global__ __launch_bounds__(256) void ogemm_mfma(const unsigned short* __restrict__ outacc_bf,
                                                  const unsigned short* __restrict__ wo,
                                                  const float* __restrict__ bo,
                                                  float* __restrict__ out, int N) {
    __shared__ unsigned short As[64 * 128];
    __shared__ unsigned short Ws[128 * 128];
    int row0 = blockIdx.x * 64;
    stage_bf_tile(As, outacc_bf, row0, N);
    stage_w(Ws, wo);
    __syncthreads();
    wave_gemm<false>(As, Ws, bo, out, nullptr, row0, N);
}

// ---- scores: wave-per-row. Lane (e,h) = (l>>3, l&7); q fragment loaded once/row. ----
__global__ __launch_bounds__(256) void scores_rows_kernel(const unsigned short* __restrict__ q_bf,
                                                          const unsigned short* __restrict__ k_bf,
                                                          const int* __restrict__ em,
                                                          const int* __restrict__ cnt,
                                                          unsigned short* __restrict__ scores_bf,
                                                          float* __restrict__ pscr, int N) {
    __shared__ float lsum[RH];
    int tid = threadIdx.x;
    if (tid < RH) lsum[tid] = 0.f;
    __syncthreads();
    int l = tid & 63;
    int e0 = l >> 3, h = l & 7;
    int wg = blockIdx.x * 4 + (tid >> 6);
    int nw = gridDim.x * 4;
    for (int row = wg; row < N; row += nw) {
        int deg = min(cnt[row], CAP);
        const uint4* qp = (const uint4*)(q_bf + (size_t)row * C_ + h * D_);
        uint4 q0 = qp[0], q1 = qp[1];
        size_t base = (size_t)row * CAP;
        for (int e = e0; e < deg; e += 8) {
            int meta = em[base + e];
            int col = meta & 0xFFFFF, t = meta >> 20;
            const uint4* kp = (const uint4*)(k_bf + (size_t)col * C_ + h * D_);
            float acc = dot8(q0, kp[0]) + dot8(q1, kp[1]);
            float val = __expf(acc * 0.25f);    // 1/sqrt(16)
            scores_bf[(base + e) * 8 + h] = f2bf(val);
            atomicAdd(&lsum[t * H_ + h], val);
        }
    }
    __syncthreads();
    if (tid < RH) pscr[blockIdx.x * RH + tid] = lsum[tid];
}

// ---- reduce per-block partials -> s[RH] (16 threads per slot, tree) ----
__global__ __launch_bounds__(640) void reduce_s_kernel(const float* __restrict__ pscr,
                                                       float* __restrict__ s, int nb) {
    __shared__ float red[640];
    int t = threadIdx.x;
    int slot = t >> 4;          // 0..39
    int g = t & 15;
    float sum = 0.f;
    for (int b = g; b < nb; b += 16) sum += pscr[b * RH + slot];
    red[t] = sum;
    __syncthreads();
    for (int d = 8; d > 0; d >>= 1) {
        if (g < d) red[t] += red[t + d];
        __syncthreads();
    }
    if (g == 0) s[slot] = red[t];
}

// ---- gather: one row per 64-thread block; 4-edge unroll; writes bf16*alpha ----
__global__ __launch_bounds__(64) void gather_kernel(const unsigned short* __restrict__ scores_bf,
                                                    const unsigned short* __restrict__ v_bf,
                                                    const int* __restrict__ em,
                                                    const int* __restrict__ cnt,
                                                    const float* __restrict__ s,
                                                    const float* __restrict__ alpha,
                                                    unsigned short* __restrict__ outacc_bf) {
    __shared__ float sinv[RH];
    int tid = threadIdx.x;
    if (tid < RH) { float sv = s[tid]; sinv[tid] = sv > 0.f ? 1.f / sv : 0.f; }
    __syncthreads();
    int row = blockIdx.x;
    int deg = min(cnt[row], CAP);
    size_t base = (size_t)row * CAP;
    int c0 = tid * 2;            // two output channels per lane
    int h = c0 >> 4;             // head for both channels
    float ax = 0.f, ay = 0.f;
    int j = 0;
    for (; j + 3 < deg; j += 4) {
        int y0 = em[base + j], y1 = em[base + j + 1], y2 = em[base + j + 2], y3 = em[base + j + 3];
        float a0 = bf2f(scores_bf[(base + j + 0) * 8 + h]) * sinv[(y0 >> 20) * H_ + h];
        float a1 = bf2f(scores_bf[(base + j + 1) * 8 + h]) * sinv[(y1 >> 20) * H_ + h];
        float a2 = bf2f(scores_bf[(base + j + 2) * 8 + h]) * sinv[(y2 >> 20) * H_ + h];
        float a3 = bf2f(scores_bf[(base + j + 3) * 8 + h]) * sinv[(y3 >> 20) * H_ + h];
        unsigned int p0 = *(const unsigned int*)(v_bf + (size_t)(y0 & 0xFFFFF) * C_ + c0);
        unsigned int p1 = *(const unsigned int*)(v_bf + (size_t)(y1 & 0xFFFFF) * C_ + c0);
        unsigned int p2 = *(const unsigned int*)(v_bf + (size_t)(y2 & 0xFFFFF) * C_ + c0);
        unsigned int p3 = *(const unsigned int*)(v_bf + (size_t)(y3 & 0xFFFFF) * C_ + c0);
        ax += bf2f((unsigned short)p0) * a0 + bf2f((unsigned short)p1) * a1
            + bf2f((unsigned short)p2) * a2 + bf2f((unsigned short)p3) * a3;
        ay += bf2f((unsigned short)(p0 >> 16)) * a0 + bf2f((unsigned short)(p1 >> 16)) * a1
            + bf2f((unsigned short)(p2 >> 16)) * a2 + bf2f((unsigned short)(p3 >> 16)) * a3;
    }
    for (; j < deg; ++j) {
        int y0 = em[base + j];
        float a0 = bf2f(scores_bf[(base + j) * 8 + h]) * sinv[(y0 >> 20) * H_ + h];
        unsigned int p0 = *(const unsigned int*)(v_bf + (size_t)(y0 & 0xFFFFF) * C_ + c0);
        ax += bf2f((unsigned short)p0) * a0;
        ay += bf2f((unsigned short)(p0 >> 16)) * a0;
    }
    float2 al = *(const float2*)(alpha + c0);
    unsigned int pk = (unsigned int)f2bf(ax * al.x) | ((unsigned int)f2bf(ay * al.y) << 16);
    *(unsigned int*)(outacc_bf + (size_t)row * C_ + c0) = pk;
}

extern "C" void kernel_launch(void* const* d_in, const int* in_sizes, int n_in,
                              void* d_out, int out_size, void* d_ws, size_t ws_size,
                              hipStream_t stream) {
    const float* x  = (const float*)d_in[0];
    const int*   ei = (const int*)d_in[1];
    const int*   et = (const int*)d_in[2];
    // d_in[3] = num_relations (scalar) — R_ hardcoded to 5 per problem setup
    const float* Wq = (const float*)d_in[4];
    const float* bq = (const float*)d_in[5];
    const float* Wk = (const float*)d_in[6];
    const float* bk = (const float*)d_in[7];
    const float* Wv = (const float*)d_in[8];
    const float* bv = (const float*)d_in[9];
    const float* sa = (const float*)d_in[10];
    const float* Wo = (const float*)d_in[11];
    const float* bo = (const float*)d_in[12];
    float* out = (float*)d_out;

    int N = in_sizes[0] / C_;
    int E = in_sizes[2];
    int NB = (N + RPB - 1) / RPB;     // coarse bins

    // layout (8B-aligned sections):
    unsigned short* q_bf = (unsigned short*)d_ws;            // N*C bf16
    unsigned short* k_bf = q_bf + (size_t)N * C_;            // N*C bf16
    unsigned short* v_bf = k_bf + (size_t)N * C_;            // N*C bf16
    unsigned short* scores_bf = v_bf + (size_t)N * C_;       // N*CAP*8 bf16
    float* s      = (float*)(scores_bf + (size_t)N * CAP * H_);  // RH
    float* alpha  = s + RH;                                  // C
    int*   em     = (int*)(alpha + C_);                      // N*CAP ints (col|type<<20)
    int*   cnt    = em + (size_t)N * CAP;                    // N ints (degree)
    int*   bins   = cnt + N;                                 // NB*BCAP ints (pass-1 bins)
    int*   bcnt   = bins + (size_t)NB * BCAP;                // NB ints
    unsigned short* w3 = (unsigned short*)(bcnt + NB + (NB & 1));  // 3*16384 bf16
    unsigned short* wo = w3 + 3 * 16384;                     // 16384 bf16
    float* pscr   = (float*)(wo + 16384);                    // SC_BLOCKS*RH
    unsigned short* outacc_bf = q_bf;   // alias: q_bf dead after scores
    size_t need = (size_t)((char*)(pscr + SC_BLOCKS * RH) - (char*)d_ws);
    if (ws_size < need) return;   // workspace too small — fail cleanly

    (void)hipMemsetAsync(bcnt, 0, (size_t)NB * sizeof(int), stream);
    wprep_init_kernel<<<64, 256, 0, stream>>>(Wq, Wk, Wv, Wo, sa, w3, wo, alpha);

    // fused pass-1 binning + qkv GEMM (independent work, 4:3 interleave)
    int nfb = (E + 255) / 256;
    int nrt = (N + 63) / 64;
    int nq3 = nrt * 3;
    int ngroups = max((nfb + 3) / 4, (nq3 + 2) / 3);
    fill_qkv_kernel<<<ngroups * 7, 256, 0, stream>>>(ei, et, bcnt, bins, x, w3, bq, bk, bv,
                                                     q_bf, k_bf, v_bf, N, E, nfb, nq3);
    binscat_kernel<<<NB, 256, 0, stream>>>(bins, bcnt, em, cnt, N);

    scores_rows_kernel<<<SC_BLOCKS, 256, 0, stream>>>(q_bf, k_bf, em, cnt, scores_bf, pscr, N);
    reduce_s_kernel<<<1, 640, 0, stream>>>(pscr, s, SC_BLOCKS);
    gather_kernel<<<N, 64, 0, stream>>>(scores_bf, v_bf, em, cnt, s, alpha, outacc_bf);
    ogemm_mfma<<<nrt, 256, 0, stream>>>(outacc_bf, wo, bo, out, N);
}

// Round 16
// 197.631 us; speedup vs baseline: 1.7272x; 1.7272x over previous
//
#include <hip/hip_runtime.h>

constexpr int R_ = 5, H_ = 8, D_ = 16, C_ = 128;
constexpr int RH = R_ * H_;       // 40 softmax slots
constexpr int CAP = 64;           // per-row edge bucket capacity (deg ~ Poisson(16); 4 aligned sectors)
constexpr int SC_BLOCKS = 2048;   // scores grid

typedef short bf16x8 __attribute__((ext_vector_type(8)));
typedef float f32x4 __attribute__((ext_vector_type(4)));

__device__ __forceinline__ unsigned short f2bf(float f) {
    unsigned int u = __float_as_uint(f);
    u += 0x7FFFu + ((u >> 16) & 1u);   // round-to-nearest-even
    return (unsigned short)(u >> 16);
}
__device__ __forceinline__ float bf2f(unsigned short b) {
    return __uint_as_float((unsigned int)b << 16);
}
// dot of 8 bf16 pairs packed in uint4
__device__ __forceinline__ float dot8(uint4 a, uint4 b) {
    const unsigned int* pa = (const unsigned int*)&a;
    const unsigned int* pb = (const unsigned int*)&b;
    float s = 0.f;
    #pragma unroll
    for (int u = 0; u < 4; ++u) {
        s += bf2f((unsigned short)pa[u]) * bf2f((unsigned short)pb[u]);
        s += bf2f((unsigned short)(pa[u] >> 16)) * bf2f((unsigned short)(pb[u] >> 16));
    }
    return s;
}

// ---- weights to bf16 (64 blocks) + alpha init (block 0) ----
__global__ __launch_bounds__(256) void wprep_init_kernel(const float* __restrict__ Wq,
                                                         const float* __restrict__ Wk,
                                                         const float* __restrict__ Wv,
                                                         const float* __restrict__ Wo,
                                                         const float* __restrict__ sa,
                                                         unsigned short* __restrict__ w3,
                                                         unsigned short* __restrict__ wo,
                                                         float* __restrict__ alpha) {
    int i = blockIdx.x * 256 + threadIdx.x;
    if (i < 16384) {
        w3[i]           = f2bf(Wq[i]);
        w3[16384 + i]   = f2bf(Wk[i]);
        w3[32768 + i]   = f2bf(Wv[i]);
        wo[i]           = f2bf(Wo[i]);
    }
    if (blockIdx.x == 0 && threadIdx.x < D_) {
        int t = threadIdx.x;
        float vals[H_];
        float mx = -1e30f;
        #pragma unroll
        for (int h = 0; h < H_; ++h) { vals[h] = sa[h * D_ + t]; mx = fmaxf(mx, vals[h]); }
        float sum = 0.0f;
        #pragma unroll
        for (int h = 0; h < H_; ++h) { vals[h] = expf(vals[h] - mx); sum += vals[h]; }
        float inv = 1.0f / sum;
        #pragma unroll
        for (int h = 0; h < H_; ++h) alpha[h * D_ + t] = vals[h] * inv;
    }
}

// ============ MFMA GEMM pieces (operand-swap + LDS W) ============

__device__ __forceinline__ void stage_tile(unsigned short* As, const float* __restrict__ src,
                                           int row0, int N) {
    int tid = threadIdx.x;
    #pragma unroll
    for (int it = 0; it < 4; ++it) {
        int g = tid + it * 256;       // 1024 groups of 8 bf16 (16B)
        int row = g >> 4, kg = g & 15;
        int grow = row0 + row;
        float4 f0 = make_float4(0.f, 0.f, 0.f, 0.f), f1 = f0;
        if (grow < N) {
            const float* p = src + (size_t)grow * C_ + kg * 8;
            f0 = *(const float4*)p;
            f1 = *(const float4*)(p + 4);
        }
        uint4 pk;
        pk.x = f2bf(f0.x) | ((unsigned int)f2bf(f0.y) << 16);
        pk.y = f2bf(f0.z) | ((unsigned int)f2bf(f0.w) << 16);
        pk.z = f2bf(f1.x) | ((unsigned int)f2bf(f1.y) << 16);
        pk.w = f2bf(f1.z) | ((unsigned int)f2bf(f1.w) << 16);
        *(uint4*)((char*)As + (row * 256 + ((kg * 16) ^ ((row & 7) << 4)))) = pk;
    }
}

// stage a 64x128 bf16 tile (already scaled) -> swizzled LDS
__device__ __forceinline__ void stage_bf_tile(unsigned short* As,
                                              const unsigned short* __restrict__ src,
                                              int row0, int N) {
    int tid = threadIdx.x;
    #pragma unroll
    for (int it = 0; it < 4; ++it) {
        int g = tid + it * 256;
        int row = g >> 4, kg = g & 15;
        int grow = row0 + row;
        uint4 v = make_uint4(0u, 0u, 0u, 0u);
        if (grow < N) v = *(const uint4*)(src + (size_t)grow * C_ + kg * 8);
        *(uint4*)((char*)As + (row * 256 + ((kg * 16) ^ ((row & 7) << 4)))) = v;
    }
}

__device__ __forceinline__ void stage_w(unsigned short* Ws, const unsigned short* __restrict__ w) {
    int tid = threadIdx.x;
    const uint4* src = (const uint4*)w;   // 2048 x 16B
    #pragma unroll
    for (int it = 0; it < 8; ++it) {
        int g = tid + it * 256;
        int row = g >> 4, kg = g & 15;
        uint4 v = src[g];
        *(uint4*)((char*)Ws + (row * 256 + ((kg * 16) ^ ((row & 7) << 4)))) = v;
    }
}

template <bool BF_OUT>
__device__ __forceinline__ void wave_gemm(const unsigned short* As,
                                          const unsigned short* Ws,
                                          const float* __restrict__ bias,
                                          float* __restrict__ outf,
                                          unsigned short* __restrict__ outb,
                                          int row0, int N) {
    int tid = threadIdx.x;
    int l = tid & 63, wave = tid >> 6;
    int lr = l & 15, lk = (l >> 4) * 8;
    int rowA = wave * 16 + lr;                 // x-row (B-operand free index)
    const char* xbase = (const char*)As + rowA * 256;
    int swx = (rowA & 7) << 4;
    f32x4 acc[8];
    #pragma unroll
    for (int n = 0; n < 8; ++n) acc[n] = (f32x4){0.f, 0.f, 0.f, 0.f};
    #pragma unroll
    for (int kk = 0; kk < 4; ++kk) {
        bf16x8 xb = *(const bf16x8*)(xbase + (((kk * 32 + lk) * 2) ^ swx));
        #pragma unroll
        for (int n = 0; n < 8; ++n) {
            int ch = n * 16 + lr;              // W channel (A-operand free index)
            bf16x8 wf = *(const bf16x8*)((const char*)Ws + ch * 256 +
                                         (((kk * 32 + lk) * 2) ^ ((ch & 7) << 4)));
            acc[n] = __builtin_amdgcn_mfma_f32_16x16x32_bf16(wf, xb, acc[n], 0, 0, 0);
        }
    }
    int xrow = row0 + wave * 16 + lr;
    int chb = (l >> 4) * 4;
    if (xrow < N) {
        #pragma unroll
        for (int n = 0; n < 8; ++n) {
            int ch = n * 16 + chb;
            float4 b4 = *(const float4*)(bias + ch);
            float v0 = acc[n][0] + b4.x, v1 = acc[n][1] + b4.y;
            float v2 = acc[n][2] + b4.z, v3 = acc[n][3] + b4.w;
            if (BF_OUT) {
                uint2 p;
                p.x = f2bf(v0) | ((unsigned int)f2bf(v1) << 16);
                p.y = f2bf(v2) | ((unsigned int)f2bf(v3) << 16);
                *(uint2*)(outb + (size_t)xrow * C_ + ch) = p;
            } else {
                *(float4*)(outf + (size_t)xrow * C_ + ch) = make_float4(v0, v1, v2, v3);
            }
        }
    }
}

// ==== fused dispatch: bucket-fill (memory-bound, nt-store) 4:3 with qkv (MFMA) ====
__global__ __launch_bounds__(256) void fill_qkv_kernel(const int* __restrict__ ei,
                                                       const int* __restrict__ et,
                                                       int* __restrict__ cnt,
                                                       int* __restrict__ em,
                                                       const float* __restrict__ x,
                                                       const unsigned short* __restrict__ w3,
                                                       const float* __restrict__ bq,
                                                       const float* __restrict__ bk,
                                                       const float* __restrict__ bv,
                                                       unsigned short* __restrict__ q_bf,
                                                       unsigned short* __restrict__ k_bf,
                                                       unsigned short* __restrict__ v_bf,
                                                       int N, int E, int nfb, int nq3) {
    __shared__ unsigned short As[64 * 128];
    __shared__ unsigned short Ws[128 * 128];
    int bid = blockIdx.x;
    int u = bid / 7, r = bid - u * 7;
    if (r < 4) {                       // ---- bucket fill (nt scatter) ----
        int fb = u * 4 + r;
        if (fb < nfb) {
            int i = fb * 256 + threadIdx.x;
            if (i < E) {
                int row = ei[i];
                int pos = atomicAdd(&cnt[row], 1);
                if (pos < CAP)
                    __builtin_nontemporal_store(ei[E + i] | (et[i] << 20), &em[row * CAP + pos]);
            }
        }
        return;
    }
    int qb = u * 3 + (r - 4);          // ---- qkv GEMM ----
    if (qb >= nq3) return;
    int rt = qb / 3, wsel = qb - rt * 3;
    int row0 = rt * 64;
    stage_tile(As, x, row0, N);
    stage_w(Ws, w3 + wsel * 16384);
    __syncthreads();
    if (wsel == 0)      wave_gemm<true>(As, Ws, bq, nullptr, q_bf, row0, N);
    else if (wsel == 1) wave_gemm<true>(As, Ws, bk, nullptr, k_bf, row0, N);
    else                wave_gemm<true>(As, Ws, bv, nullptr, v_bf, row0, N);
}

// final GEMM: out = outacc_bf(alpha pre-applied) @ Wo^T + bo
__global__ __launch_bounds__(256) void ogemm_mfma(const unsigned short* __restrict__ outacc_bf,
                                                  const unsigned short* __restrict__ wo,
                                                  const float* __restrict__ bo,
                                                  float* __restrict__ out, int N) {
    __shared__ unsigned short As[64 * 128];
    __shared__ unsigned short Ws[128 * 128];
    int row0 = blockIdx.x * 64;
    stage_bf_tile(As, outacc_bf, row0, N);
    stage_w(Ws, wo);
    __syncthreads();
    wave_gemm<false>(As, Ws, bo, out, nullptr, row0, N);
}

// ---- scores: wave-per-row. Lane (e,h) = (l>>3, l&7); q fragment loaded once/row. ----
__global__ __launch_bounds__(256) void scores_rows_kernel(const unsigned short* __restrict__ q_bf,
                                                          const unsigned short* __restrict__ k_bf,
                                                          const int* __restrict__ em,
                                                          const int* __restrict__ cnt,
                                                          unsigned short* __restrict__ scores_bf,
                                                          float* __restrict__ pscr, int N) {
    __shared__ float lsum[RH];
    int tid = threadIdx.x;
    if (tid < RH) lsum[tid] = 0.f;
    __syncthreads();
    int l = tid & 63;
    int e0 = l >> 3, h = l & 7;
    int wg = blockIdx.x * 4 + (tid >> 6);
    int nw = gridDim.x * 4;
    for (int row = wg; row < N; row += nw) {
        int deg = min(cnt[row], CAP);
        const uint4* qp = (const uint4*)(q_bf + (size_t)row * C_ + h * D_);
        uint4 q0 = qp[0], q1 = qp[1];
        size_t base = (size_t)row * CAP;
        for (int e = e0; e < deg; e += 8) {
            int meta = em[base + e];
            int col = meta & 0xFFFFF, t = meta >> 20;
            const uint4* kp = (const uint4*)(k_bf + (size_t)col * C_ + h * D_);
            float acc = dot8(q0, kp[0]) + dot8(q1, kp[1]);
            float val = __expf(acc * 0.25f);    // 1/sqrt(16)
            __builtin_nontemporal_store(f2bf(val), &scores_bf[(base + e) * 8 + h]);
            atomicAdd(&lsum[t * H_ + h], val);
        }
    }
    __syncthreads();
    if (tid < RH) pscr[blockIdx.x * RH + tid] = lsum[tid];
}

// ---- reduce per-block partials -> s[RH] (16 threads per slot, tree) ----
__global__ __launch_bounds__(640) void reduce_s_kernel(const float* __restrict__ pscr,
                                                       float* __restrict__ s, int nb) {
    __shared__ float red[640];
    int t = threadIdx.x;
    int slot = t >> 4;          // 0..39
    int g = t & 15;
    float sum = 0.f;
    for (int b = g; b < nb; b += 16) sum += pscr[b * RH + slot];
    red[t] = sum;
    __syncthreads();
    for (int d = 8; d > 0; d >>= 1) {
        if (g < d) red[t] += red[t + d];
        __syncthreads();
    }
    if (g == 0) s[slot] = red[t];
}

// ---- gather: one row per 64-thread block; 4-edge unroll; writes bf16*alpha ----
__global__ __launch_bounds__(64) void gather_kernel(const unsigned short* __restrict__ scores_bf,
                                                    const unsigned short* __restrict__ v_bf,
                                                    const int* __restrict__ em,
                                                    const int* __restrict__ cnt,
                                                    const float* __restrict__ s,
                                                    const float* __restrict__ alpha,
                                                    unsigned short* __restrict__ outacc_bf) {
    __shared__ float sinv[RH];
    int tid = threadIdx.x;
    if (tid < RH) { float sv = s[tid]; sinv[tid] = sv > 0.f ? 1.f / sv : 0.f; }
    __syncthreads();
    int row = blockIdx.x;
    int deg = min(cnt[row], CAP);
    size_t base = (size_t)row * CAP;
    int c0 = tid * 2;            // two output channels per lane
    int h = c0 >> 4;             // head for both channels
    float ax = 0.f, ay = 0.f;
    int j = 0;
    for (; j + 3 < deg; j += 4) {
        int y0 = em[base + j], y1 = em[base + j + 1], y2 = em[base + j + 2], y3 = em[base + j + 3];
        float a0 = bf2f(scores_bf[(base + j + 0) * 8 + h]) * sinv[(y0 >> 20) * H_ + h];
        float a1 = bf2f(scores_bf[(base + j + 1) * 8 + h]) * sinv[(y1 >> 20) * H_ + h];
        float a2 = bf2f(scores_bf[(base + j + 2) * 8 + h]) * sinv[(y2 >> 20) * H_ + h];
        float a3 = bf2f(scores_bf[(base + j + 3) * 8 + h]) * sinv[(y3 >> 20) * H_ + h];
        unsigned int p0 = *(const unsigned int*)(v_bf + (size_t)(y0 & 0xFFFFF) * C_ + c0);
        unsigned int p1 = *(const unsigned int*)(v_bf + (size_t)(y1 & 0xFFFFF) * C_ + c0);
        unsigned int p2 = *(const unsigned int*)(v_bf + (size_t)(y2 & 0xFFFFF) * C_ + c0);
        unsigned int p3 = *(const unsigned int*)(v_bf + (size_t)(y3 & 0xFFFFF) * C_ + c0);
        ax += bf2f((unsigned short)p0) * a0 + bf2f((unsigned short)p1) * a1
            + bf2f((unsigned short)p2) * a2 + bf2f((unsigned short)p3) * a3;
        ay += bf2f((unsigned short)(p0 >> 16)) * a0 + bf2f((unsigned short)(p1 >> 16)) * a1
            + bf2f((unsigned short)(p2 >> 16)) * a2 + bf2f((unsigned short)(p3 >> 16)) * a3;
    }
    for (; j < deg; ++j) {
        int y0 = em[base + j];
        float a0 = bf2f(scores_bf[(base + j) * 8 + h]) * sinv[(y0 >> 20) * H_ + h];
        unsigned int p0 = *(const unsigned int*)(v_bf + (size_t)(y0 & 0xFFFFF) * C_ + c0);
        ax += bf2f((unsigned short)p0) * a0;
        ay += bf2f((unsigned short)(p0 >> 16)) * a0;
    }
    float2 al = *(const float2*)(alpha + c0);
    unsigned int pk = (unsigned int)f2bf(ax * al.x) | ((unsigned int)f2bf(ay * al.y) << 16);
    __builtin_nontemporal_store(pk, (unsigned int*)(outacc_bf + (size_t)row * C_ + c0));
}

extern "C" void kernel_launch(void* const* d_in, const int* in_sizes, int n_in,
                              void* d_out, int out_size, void* d_ws, size_t ws_size,
                              hipStream_t stream) {
    const float* x  = (const float*)d_in[0];
    const int*   ei = (const int*)d_in[1];
    const int*   et = (const int*)d_in[2];
    // d_in[3] = num_relations (scalar) — R_ hardcoded to 5 per problem setup
    const float* Wq = (const float*)d_in[4];
    const float* bq = (const float*)d_in[5];
    const float* Wk = (const float*)d_in[6];
    const float* bk = (const float*)d_in[7];
    const float* Wv = (const float*)d_in[8];
    const float* bv = (const float*)d_in[9];
    const float* sa = (const float*)d_in[10];
    const float* Wo = (const float*)d_in[11];
    const float* bo = (const float*)d_in[12];
    float* out = (float*)d_out;

    int N = in_sizes[0] / C_;
    int E = in_sizes[2];

    // layout (8B-aligned sections):
    unsigned short* q_bf = (unsigned short*)d_ws;            // N*C bf16
    unsigned short* k_bf = q_bf + (size_t)N * C_;            // N*C bf16
    unsigned short* v_bf = k_bf + (size_t)N * C_;            // N*C bf16
    unsigned short* scores_bf = v_bf + (size_t)N * C_;       // N*CAP*8 bf16
    float* s      = (float*)(scores_bf + (size_t)N * CAP * H_);  // RH
    float* alpha  = s + RH;                                  // C
    int*   em     = (int*)(alpha + C_);                      // N*CAP ints (col|type<<20)
    int*   cnt    = em + (size_t)N * CAP;                    // N ints (degree)
    unsigned short* w3 = (unsigned short*)(cnt + N);         // 3*16384 bf16
    unsigned short* wo = w3 + 3 * 16384;                     // 16384 bf16
    float* pscr   = (float*)(wo + 16384);                    // SC_BLOCKS*RH
    unsigned short* outacc_bf = q_bf;   // alias: q_bf dead after scores
    size_t need = (size_t)((char*)(pscr + SC_BLOCKS * RH) - (char*)d_ws);
    if (ws_size < need) return;   // workspace too small — fail cleanly

    (void)hipMemsetAsync(cnt, 0, (size_t)N * sizeof(int), stream);
    wprep_init_kernel<<<64, 256, 0, stream>>>(Wq, Wk, Wv, Wo, sa, w3, wo, alpha);

    // fused bucket-fill + qkv GEMM (independent work, 4:3 interleave)
    int nfb = (E + 255) / 256;
    int nrt = (N + 63) / 64;
    int nq3 = nrt * 3;
    int ngroups = max((nfb + 3) / 4, (nq3 + 2) / 3);
    fill_qkv_kernel<<<ngroups * 7, 256, 0, stream>>>(ei, et, cnt, em, x, w3, bq, bk, bv,
                                                     q_bf, k_bf, v_bf, N, E, nfb, nq3);

    scores_rows_kernel<<<SC_BLOCKS, 256, 0, stream>>>(q_bf, k_bf, em, cnt, scores_bf, pscr, N);
    reduce_s_kernel<<<1, 640, 0, stream>>>(pscr, s, SC_BLOCKS);
    gather_kernel<<<N, 64, 0, stream>>>(scores_bf, v_bf, em, cnt, s, alpha, outacc_bf);
    ogemm_mfma<<<nrt, 256, 0, stream>>>(outacc_bf, wo, bo, out, N);
}

// Round 17
// 188.853 us; speedup vs baseline: 1.8075x; 1.0465x over previous
//
#include <hip/hip_runtime.h>

constexpr int R_ = 5, H_ = 8, D_ = 16, C_ = 128;
constexpr int RH = R_ * H_;       // 40 softmax slots
constexpr int CAP = 56;           // per-row edge bucket capacity (deg ~ Poisson(16))
constexpr int SC_BLOCKS = 2048;   // scores grid

typedef short bf16x8 __attribute__((ext_vector_type(8)));
typedef float f32x4 __attribute__((ext_vector_type(4)));

__device__ __forceinline__ unsigned short f2bf(float f) {
    unsigned int u = __float_as_uint(f);
    u += 0x7FFFu + ((u >> 16) & 1u);   // round-to-nearest-even
    return (unsigned short)(u >> 16);
}
__device__ __forceinline__ float bf2f(unsigned short b) {
    return __uint_as_float((unsigned int)b << 16);
}
// dot of 8 bf16 pairs packed in uint4
__device__ __forceinline__ float dot8(uint4 a, uint4 b) {
    const unsigned int* pa = (const unsigned int*)&a;
    const unsigned int* pb = (const unsigned int*)&b;
    float s = 0.f;
    #pragma unroll
    for (int u = 0; u < 4; ++u) {
        s += bf2f((unsigned short)pa[u]) * bf2f((unsigned short)pb[u]);
        s += bf2f((unsigned short)(pa[u] >> 16)) * bf2f((unsigned short)(pb[u] >> 16));
    }
    return s;
}

// ---- weights to bf16 (64 blocks) + alpha init (block 0) + cnt zeroing ----
__global__ __launch_bounds__(256) void wprep_init_kernel(const float* __restrict__ Wq,
                                                         const float* __restrict__ Wk,
                                                         const float* __restrict__ Wv,
                                                         const float* __restrict__ Wo,
                                                         const float* __restrict__ sa,
                                                         unsigned short* __restrict__ w3,
                                                         unsigned short* __restrict__ wo,
                                                         float* __restrict__ alpha,
                                                         int* __restrict__ cnt, int N) {
    int i = blockIdx.x * 256 + threadIdx.x;
    if (i < 16384) {
        w3[i]           = f2bf(Wq[i]);
        w3[16384 + i]   = f2bf(Wk[i]);
        w3[32768 + i]   = f2bf(Wv[i]);
        wo[i]           = f2bf(Wo[i]);
    }
    #pragma unroll
    for (int u = 0; u < 4; ++u) {
        int idx = i + u * 16384;
        if (idx < N) cnt[idx] = 0;
    }
    if (blockIdx.x == 0 && threadIdx.x < D_) {
        int t = threadIdx.x;
        float vals[H_];
        float mx = -1e30f;
        #pragma unroll
        for (int h = 0; h < H_; ++h) { vals[h] = sa[h * D_ + t]; mx = fmaxf(mx, vals[h]); }
        float sum = 0.0f;
        #pragma unroll
        for (int h = 0; h < H_; ++h) { vals[h] = expf(vals[h] - mx); sum += vals[h]; }
        float inv = 1.0f / sum;
        #pragma unroll
        for (int h = 0; h < H_; ++h) alpha[h * D_ + t] = vals[h] * inv;
    }
}

// ============ MFMA GEMM pieces (operand-swap + LDS W) ============

__device__ __forceinline__ void stage_tile(unsigned short* As, const float* __restrict__ src,
                                           int row0, int N) {
    int tid = threadIdx.x;
    #pragma unroll
    for (int it = 0; it < 4; ++it) {
        int g = tid + it * 256;       // 1024 groups of 8 bf16 (16B)
        int row = g >> 4, kg = g & 15;
        int grow = row0 + row;
        float4 f0 = make_float4(0.f, 0.f, 0.f, 0.f), f1 = f0;
        if (grow < N) {
            const float* p = src + (size_t)grow * C_ + kg * 8;
            f0 = *(const float4*)p;
            f1 = *(const float4*)(p + 4);
        }
        uint4 pk;
        pk.x = f2bf(f0.x) | ((unsigned int)f2bf(f0.y) << 16);
        pk.y = f2bf(f0.z) | ((unsigned int)f2bf(f0.w) << 16);
        pk.z = f2bf(f1.x) | ((unsigned int)f2bf(f1.y) << 16);
        pk.w = f2bf(f1.z) | ((unsigned int)f2bf(f1.w) << 16);
        *(uint4*)((char*)As + (row * 256 + ((kg * 16) ^ ((row & 7) << 4)))) = pk;
    }
}

// stage a 64x128 bf16 tile (already scaled) -> swizzled LDS
__device__ __forceinline__ void stage_bf_tile(unsigned short* As,
                                              const unsigned short* __restrict__ src,
                                              int row0, int N) {
    int tid = threadIdx.x;
    #pragma unroll
    for (int it = 0; it < 4; ++it) {
        int g = tid + it * 256;
        int row = g >> 4, kg = g & 15;
        int grow = row0 + row;
        uint4 v = make_uint4(0u, 0u, 0u, 0u);
        if (grow < N) v = *(const uint4*)(src + (size_t)grow * C_ + kg * 8);
        *(uint4*)((char*)As + (row * 256 + ((kg * 16) ^ ((row & 7) << 4)))) = v;
    }
}

__device__ __forceinline__ void stage_w(unsigned short* Ws, const unsigned short* __restrict__ w) {
    int tid = threadIdx.x;
    const uint4* src = (const uint4*)w;   // 2048 x 16B
    #pragma unroll
    for (int it = 0; it < 8; ++it) {
        int g = tid + it * 256;
        int row = g >> 4, kg = g & 15;
        uint4 v = src[g];
        *(uint4*)((char*)Ws + (row * 256 + ((kg * 16) ^ ((row & 7) << 4)))) = v;
    }
}

template <bool BF_OUT>
__device__ __forceinline__ void wave_gemm(const unsigned short* As,
                                          const unsigned short* Ws,
                                          const float* __restrict__ bias,
                                          float* __restrict__ outf,
                                          unsigned short* __restrict__ outb,
                                          int row0, int N) {
    int tid = threadIdx.x;
    int l = tid & 63, wave = tid >> 6;
    int lr = l & 15, lk = (l >> 4) * 8;
    int rowA = wave * 16 + lr;                 // x-row (B-operand free index)
    const char* xbase = (const char*)As + rowA * 256;
    int swx = (rowA & 7) << 4;
    f32x4 acc[8];
    #pragma unroll
    for (int n = 0; n < 8; ++n) acc[n] = (f32x4){0.f, 0.f, 0.f, 0.f};
    #pragma unroll
    for (int kk = 0; kk < 4; ++kk) {
        bf16x8 xb = *(const bf16x8*)(xbase + (((kk * 32 + lk) * 2) ^ swx));
        #pragma unroll
        for (int n = 0; n < 8; ++n) {
            int ch = n * 16 + lr;              // W channel (A-operand free index)
            bf16x8 wf = *(const bf16x8*)((const char*)Ws + ch * 256 +
                                         (((kk * 32 + lk) * 2) ^ ((ch & 7) << 4)));
            acc[n] = __builtin_amdgcn_mfma_f32_16x16x32_bf16(wf, xb, acc[n], 0, 0, 0);
        }
    }
    int xrow = row0 + wave * 16 + lr;
    int chb = (l >> 4) * 4;
    if (xrow < N) {
        #pragma unroll
        for (int n = 0; n < 8; ++n) {
            int ch = n * 16 + chb;
            float4 b4 = *(const float4*)(bias + ch);
            float v0 = acc[n][0] + b4.x, v1 = acc[n][1] + b4.y;
            float v2 = acc[n][2] + b4.z, v3 = acc[n][3] + b4.w;
            if (BF_OUT) {
                uint2 p;
                p.x = f2bf(v0) | ((unsigned int)f2bf(v1) << 16);
                p.y = f2bf(v2) | ((unsigned int)f2bf(v3) << 16);
                *(uint2*)(outb + (size_t)xrow * C_ + ch) = p;
            } else {
                *(float4*)(outf + (size_t)xrow * C_ + ch) = make_float4(v0, v1, v2, v3);
            }
        }
    }
}

// ==== fused dispatch: bucket-fill (memory-bound, nt-store) 4:3 with qkv (MFMA) ====
__global__ __launch_bounds__(256) void fill_qkv_kernel(const int* __restrict__ ei,
                                                       const int* __restrict__ et,
                                                       int* __restrict__ cnt,
                                                       int* __restrict__ em,
                                                       const float* __restrict__ x,
                                                       const unsigned short* __restrict__ w3,
                                                       const float* __restrict__ bq,
                                                       const float* __restrict__ bk,
                                                       const float* __restrict__ bv,
                                                       unsigned short* __restrict__ q_bf,
                                                       unsigned short* __restrict__ k_bf,
                                                       unsigned short* __restrict__ v_bf,
                                                       int N, int E, int nfb, int nq3) {
    __shared__ unsigned short As[64 * 128];
    __shared__ unsigned short Ws[128 * 128];
    int bid = blockIdx.x;
    int u = bid / 7, r = bid - u * 7;
    if (r < 4) {                       // ---- bucket fill (nt scatter) ----
        int fb = u * 4 + r;
        if (fb < nfb) {
            int i = fb * 256 + threadIdx.x;
            if (i < E) {
                int row = ei[i];
                int pos = atomicAdd(&cnt[row], 1);
                if (pos < CAP)
                    __builtin_nontemporal_store(ei[E + i] | (et[i] << 20), &em[row * CAP + pos]);
            }
        }
        return;
    }
    int qb = u * 3 + (r - 4);          // ---- qkv GEMM ----
    if (qb >= nq3) return;
    int rt = qb / 3, wsel = qb - rt * 3;
    int row0 = rt * 64;
    stage_tile(As, x, row0, N);
    stage_w(Ws, w3 + wsel * 16384);
    __syncthreads();
    if (wsel == 0)      wave_gemm<true>(As, Ws, bq, nullptr, q_bf, row0, N);
    else if (wsel == 1) wave_gemm<true>(As, Ws, bk, nullptr, k_bf, row0, N);
    else                wave_gemm<true>(As, Ws, bv, nullptr, v_bf, row0, N);
}

// final GEMM: out = outacc_bf(alpha pre-applied) @ Wo^T + bo
__global__ __launch_bounds__(256) void ogemm_mfma(const unsigned short* __restrict__ outacc_bf,
                                                  const unsigned short* __restrict__ wo,
                                                  const float* __restrict__ bo,
                                                  float* __restrict__ out, int N) {
    __shared__ unsigned short As[64 * 128];
    __shared__ unsigned short Ws[128 * 128];
    int row0 = blockIdx.x * 64;
    stage_bf_tile(As, outacc_bf, row0, N);
    stage_w(Ws, wo);
    __syncthreads();
    wave_gemm<false>(As, Ws, bo, out, nullptr, row0, N);
}

// ---- scores: wave-per-row. Lane (e,h) = (l>>3, l&7); q fragment loaded once/row. ----
__global__ __launch_bounds__(256) void scores_rows_kernel(const unsigned short* __restrict__ q_bf,
                                                          const unsigned short* __restrict__ k_bf,
                                                          const int* __restrict__ em,
                                                          const int* __restrict__ cnt,
                                                          unsigned short* __restrict__ scores_bf,
                                                          float* __restrict__ pscr, int N) {
    __shared__ float lsum[RH];
    int tid = threadIdx.x;
    if (tid < RH) lsum[tid] = 0.f;
    __syncthreads();
    int l = tid & 63;
    int e0 = l >> 3, h = l & 7;
    int wg = blockIdx.x * 4 + (tid >> 6);
    int nw = gridDim.x * 4;
    for (int row = wg; row < N; row += nw) {
        int deg = min(cnt[row], CAP);
        const uint4* qp = (const uint4*)(q_bf + (size_t)row * C_ + h * D_);
        uint4 q0 = qp[0], q1 = qp[1];
        size_t base = (size_t)row * CAP;
        for (int e = e0; e < deg; e += 8) {
            int meta = em[base + e];
            int col = meta & 0xFFFFF, t = meta >> 20;
            const uint4* kp = (const uint4*)(k_bf + (size_t)col * C_ + h * D_);
            float acc = dot8(q0, kp[0]) + dot8(q1, kp[1]);
            float val = __expf(acc * 0.25f);    // 1/sqrt(16)
            scores_bf[(base + e) * 8 + h] = f2bf(val);
            atomicAdd(&lsum[t * H_ + h], val);
        }
    }
    __syncthreads();
    if (tid < RH) pscr[blockIdx.x * RH + tid] = lsum[tid];
}

// ---- reduce per-block partials -> s[RH] (16 threads per slot, tree) ----
__global__ __launch_bounds__(640) void reduce_s_kernel(const float* __restrict__ pscr,
                                                       float* __restrict__ s, int nb) {
    __shared__ float red[640];
    int t = threadIdx.x;
    int slot = t >> 4;          // 0..39
    int g = t & 15;
    float sum = 0.f;
    for (int b = g; b < nb; b += 16) sum += pscr[b * RH + slot];
    red[t] = sum;
    __syncthreads();
    for (int d = 8; d > 0; d >>= 1) {
        if (g < d) red[t] += red[t + d];
        __syncthreads();
    }
    if (g == 0) s[slot] = red[t];
}

// ---- gather: one row per 64-thread block; 4-edge unroll; writes bf16*alpha ----
__global__ __launch_bounds__(64) void gather_kernel(const unsigned short* __restrict__ scores_bf,
                                                    const unsigned short* __restrict__ v_bf,
                                                    const int* __restrict__ em,
                                                    const int* __restrict__ cnt,
                                                    const float* __restrict__ s,
                                                    const float* __restrict__ alpha,
                                                    unsigned short* __restrict__ outacc_bf) {
    __shared__ float sinv[RH];
    int tid = threadIdx.x;
    if (tid < RH) { float sv = s[tid]; sinv[tid] = sv > 0.f ? 1.f / sv : 0.f; }
    __syncthreads();
    int row = blockIdx.x;
    int deg = min(cnt[row], CAP);
    size_t base = (size_t)row * CAP;
    int c0 = tid * 2;            // two output channels per lane
    int h = c0 >> 4;             // head for both channels
    float ax = 0.f, ay = 0.f;
    int j = 0;
    for (; j + 3 < deg; j += 4) {
        int y0 = em[base + j], y1 = em[base + j + 1], y2 = em[base + j + 2], y3 = em[base + j + 3];
        float a0 = bf2f(scores_bf[(base + j + 0) * 8 + h]) * sinv[(y0 >> 20) * H_ + h];
        float a1 = bf2f(scores_bf[(base + j + 1) * 8 + h]) * sinv[(y1 >> 20) * H_ + h];
        float a2 = bf2f(scores_bf[(base + j + 2) * 8 + h]) * sinv[(y2 >> 20) * H_ + h];
        float a3 = bf2f(scores_bf[(base + j + 3) * 8 + h]) * sinv[(y3 >> 20) * H_ + h];
        unsigned int p0 = *(const unsigned int*)(v_bf + (size_t)(y0 & 0xFFFFF) * C_ + c0);
        unsigned int p1 = *(const unsigned int*)(v_bf + (size_t)(y1 & 0xFFFFF) * C_ + c0);
        unsigned int p2 = *(const unsigned int*)(v_bf + (size_t)(y2 & 0xFFFFF) * C_ + c0);
        unsigned int p3 = *(const unsigned int*)(v_bf + (size_t)(y3 & 0xFFFFF) * C_ + c0);
        ax += bf2f((unsigned short)p0) * a0 + bf2f((unsigned short)p1) * a1
            + bf2f((unsigned short)p2) * a2 + bf2f((unsigned short)p3) * a3;
        ay += bf2f((unsigned short)(p0 >> 16)) * a0 + bf2f((unsigned short)(p1 >> 16)) * a1
            + bf2f((unsigned short)(p2 >> 16)) * a2 + bf2f((unsigned short)(p3 >> 16)) * a3;
    }
    for (; j < deg; ++j) {
        int y0 = em[base + j];
        float a0 = bf2f(scores_bf[(base + j) * 8 + h]) * sinv[(y0 >> 20) * H_ + h];
        unsigned int p0 = *(const unsigned int*)(v_bf + (size_t)(y0 & 0xFFFFF) * C_ + c0);
        ax += bf2f((unsigned short)p0) * a0;
        ay += bf2f((unsigned short)(p0 >> 16)) * a0;
    }
    float2 al = *(const float2*)(alpha + c0);
    unsigned int pk = (unsigned int)f2bf(ax * al.x) | ((unsigned int)f2bf(ay * al.y) << 16);
    *(unsigned int*)(outacc_bf + (size_t)row * C_ + c0) = pk;
}

extern "C" void kernel_launch(void* const* d_in, const int* in_sizes, int n_in,
                              void* d_out, int out_size, void* d_ws, size_t ws_size,
                              hipStream_t stream) {
    const float* x  = (const float*)d_in[0];
    const int*   ei = (const int*)d_in[1];
    const int*   et = (const int*)d_in[2];
    // d_in[3] = num_relations (scalar) — R_ hardcoded to 5 per problem setup
    const float* Wq = (const float*)d_in[4];
    const float* bq = (const float*)d_in[5];
    const float* Wk = (const float*)d_in[6];
    const float* bk = (const float*)d_in[7];
    const float* Wv = (const float*)d_in[8];
    const float* bv = (const float*)d_in[9];
    const float* sa = (const float*)d_in[10];
    const float* Wo = (const float*)d_in[11];
    const float* bo = (const float*)d_in[12];
    float* out = (float*)d_out;

    int N = in_sizes[0] / C_;
    int E = in_sizes[2];

    // layout (8B-aligned sections):
    unsigned short* q_bf = (unsigned short*)d_ws;            // N*C bf16
    unsigned short* k_bf = q_bf + (size_t)N * C_;            // N*C bf16
    unsigned short* v_bf = k_bf + (size_t)N * C_;            // N*C bf16
    unsigned short* scores_bf = v_bf + (size_t)N * C_;       // N*CAP*8 bf16
    float* s      = (float*)(scores_bf + (size_t)N * CAP * H_);  // RH
    float* alpha  = s + RH;                                  // C
    int*   em     = (int*)(alpha + C_);                      // N*CAP ints (col|type<<20)
    int*   cnt    = em + (size_t)N * CAP;                    // N ints (degree)
    unsigned short* w3 = (unsigned short*)(cnt + N);         // 3*16384 bf16
    unsigned short* wo = w3 + 3 * 16384;                     // 16384 bf16
    float* pscr   = (float*)(wo + 16384);                    // SC_BLOCKS*RH
    unsigned short* outacc_bf = q_bf;   // alias: q_bf dead after scores
    size_t need = (size_t)((char*)(pscr + SC_BLOCKS * RH) - (char*)d_ws);
    if (ws_size < need) return;   // workspace too small — fail cleanly

    wprep_init_kernel<<<64, 256, 0, stream>>>(Wq, Wk, Wv, Wo, sa, w3, wo, alpha, cnt, N);

    // fused bucket-fill + qkv GEMM (independent work, 4:3 interleave)
    int nfb = (E + 255) / 256;
    int nrt = (N + 63) / 64;
    int nq3 = nrt * 3;
    int ngroups = max((nfb + 3) / 4, (nq3 + 2) / 3);
    fill_qkv_kernel<<<ngroups * 7, 256, 0, stream>>>(ei, et, cnt, em, x, w3, bq, bk, bv,
                                                     q_bf, k_bf, v_bf, N, E, nfb, nq3);

    scores_rows_kernel<<<SC_BLOCKS, 256, 0, stream>>>(q_bf, k_bf, em, cnt, scores_bf, pscr, N);
    reduce_s_kernel<<<1, 640, 0, stream>>>(pscr, s, SC_BLOCKS);
    gather_kernel<<<N, 64, 0, stream>>>(scores_bf, v_bf, em, cnt, s, alpha, outacc_bf);
    ogemm_mfma<<<nrt, 256, 0, stream>>>(outacc_bf, wo, bo, out, N);
}